// Round 7
// baseline (114.944 us; speedup 1.0000x reference)
//
#include <hip/hip_runtime.h>
#include <hip/hip_fp16.h>
#include <math.h>

// Problem constants (match reference)
#define NCURVES   256
#define GPER      64               // NUM_BEZIERS * NUM_SAMPLES = 2*32
#define NUM_G     (NCURVES*GPER)   // 16384
#define IMG_W     256
#define IMG_H     256
#define TILE      16
#define TILES_X   (IMG_W/TILE)     // 16
#define TILES_Y   (IMG_H/TILE)     // 16
#define NTILES    (TILES_X*TILES_Y) // 256
#define REC_F     8

#define A_MIN     3.0e-6f          // alpha cutoff for tile bbox
#define P_CUT     (-12.6f)         // per-pixel power cutoff (consistent with A_MIN)
#define T_EPS     1.0e-5f          // transmittance early-out (residual <= 1e-5)

#define SEGS      8                // depth slices (32 curves each) -> cross-CU split
#define CPS       (NCURVES/SEGS)   // 32 curves per slice
#define CPW       (CPS/4)          // 8 curves per wave
#define CAP       224              // per-wave record capacity (realistic max ~60)

// ---------------------------------------------------------------------------
// Kernel 1 (render_fused): grid = (tile, seg) = 2048 blocks x 256 threads.
// PREP IS FUSED IN (round-7 change): kernel count 3 -> 2. R6 analysis showed
// our kernels total ~7us inside an 83us iteration -- the budget is dispatch
// boundaries, so delete one. Each block:
//   1. depths -> LDS; 256-thread stable-rank recompute (broadcast reads,
//      ~1.5k cyc) -> the 32 curves whose rank lies in this seg's slice.
//   2. Wave w preps curves rank-slot [w*8,(w+1)*8): full verified prep math
//      (conic/color/alpha/bezier mean, 64 lanes = 64 samples), tests the
//      SAME clamped-int bbox predicate as rounds 0-6 against THIS tile, and
//      ballot-compacts hit records straight into a wave-private LDS list.
//      Ascending (u, lane) = ascending (rank, sample) = sorted-gi order;
//      wave lists concat depth-ordered. recs/bbox never touch memory.
//   3. Composite from LDS (R6's vote-free unrolled body, early-out at
//      32-iter boundaries), write float4 partial per pixel.
// LDS ~29.8 KB -> 5 blocks/CU. Slice boundaries at fixed rank ranges are
// depth-contiguous -> kernel-2 associative combine stays exact.
// ---------------------------------------------------------------------------
__global__ __launch_bounds__(256)
void render_fused(const float* __restrict__ ctrl,        // [256][10][2]
                  const float* __restrict__ features,    // [256][3]
                  const float* __restrict__ cholesky,    // [256][3]
                  const float* __restrict__ opacity,     // [256]
                  const float* __restrict__ depth,       // [256]
                  float4*      __restrict__ partial)     // [SEGS][IMG_H*IMG_W]
{
    __shared__ float4        lrec[4][CAP][2];   // 28.7 KB: per-wave ordered records
    __shared__ float         dsh[NCURVES];      // 1 KB
    __shared__ unsigned char lcur[CPS];         // rank-slot -> curve id
    __shared__ unsigned      wn[4];

    int tid   = threadIdx.x;
    int seg   = blockIdx.x & (SEGS-1);
    int tile  = blockIdx.x >> 3;            // 0..255
    int tilex = tile & (TILES_X-1);
    int tiley = tile >> 4;

    int lane = tid & 63;
    int wid  = tid >> 6;                    // 0..3
    unsigned long long lmask = (1ull << lane) - 1ull;

    // ---- 1: depths to LDS, stable rank, slice membership
    if (tid < NCURVES) dsh[tid] = depth[tid];
    __syncthreads();

    if (tid < NCURVES) {
        float dc = dsh[tid];
        int r = 0;
        for (int j = 0; j < NCURVES; ++j) {       // LDS broadcast per iter
            float dj = dsh[j];
            r += (dj < dc) || (dj == dc && j < tid);
        }
        int slot = r - seg*CPS;                   // rank within this slice?
        if ((unsigned)slot < (unsigned)CPS) lcur[slot] = (unsigned char)tid;
    }
    __syncthreads();

    // ---- 2: per-wave prep + ordered ballot-compact (verbatim prep math)
    int cnt = 0;
    #pragma unroll 1
    for (int u = 0; u < CPW; ++u) {
        int c = (int)lcur[wid*CPW + u];           // LDS broadcast

        float c0 = cholesky[3*c+0] + 0.5f;
        float c1 = cholesky[3*c+1];
        float c2 = cholesky[3*c+2] + 0.5f;
        float s00 = c0*c0;
        float s01 = c0*c1;
        float s11 = c1*c1 + c2*c2;
        float inv = 1.0f / (s00*s11 - s01*s01);
        float A  =  s11*inv;
        float Bc = -s01*inv;
        float Cc =  s00*inv;

        float cr = 1.0f/(1.0f + __expf(-features[3*c+0]));
        float cg = 1.0f/(1.0f + __expf(-features[3*c+1]));
        float cb = 1.0f/(1.0f + __expf(-features[3*c+2]));
        float al = 1.0f/(1.0f + __expf(-opacity[c]));

        float cut = fmaxf(2.0f*(__logf(al) - __logf(A_MIN)), 0.0f);
        float rx = sqrtf(cut * s00);
        float ry = sqrtf(cut * s11);

        int k = lane >> 5;              // bezier segment 0/1
        int s = lane & 31;              // sample 0..31
        float t = 0.007f + (float)s * (0.986f/31.0f);
        float uu = 1.0f - t;
        float t2=t*t, t3=t2*t, t4=t3*t, t5=t4*t;
        float u2=uu*uu, u3=u2*uu, u4=u3*uu, u5=u4*uu;
        float w6[6] = { u5, 5.0f*t*u4, 10.0f*t2*u3, 10.0f*t3*u2, 5.0f*t4*uu, t5 };

        const float* cp = ctrl + c*20;
        float px = 0.0f, py = 0.0f;
        #pragma unroll
        for (int j = 0; j < 6; ++j) {
            int idx = (k*5 + j) % 10;   // seg0: 0..5 ; seg1: 5,6,7,8,9,0
            px += w6[j]*cp[2*idx+0];
            py += w6[j]*cp[2*idx+1];
        }
        float mx = (tanhf(px)*0.5f + 0.5f) * (float)IMG_W;
        float my = (tanhf(py)*0.5f + 0.5f) * (float)IMG_H;

        // same clamped-int bbox predicate as rounds 0-6
        int tx0 = min(max((int)floorf((mx - rx) * (1.0f/TILE)), 0), TILES_X-1);
        int tx1 = min(max((int)floorf((mx + rx) * (1.0f/TILE)), 0), TILES_X-1);
        int ty0 = min(max((int)floorf((my - ry) * (1.0f/TILE)), 0), TILES_Y-1);
        int ty1 = min(max((int)floorf((my + ry) * (1.0f/TILE)), 0), TILES_Y-1);
        bool pred = (tilex >= tx0) & (tilex <= tx1) &
                    (tiley >= ty0) & (tiley <= ty1);

        unsigned long long m = __ballot(pred ? 1 : 0);
        if (pred) {
            int pos = cnt + (int)__popcll(m & lmask);
            if (pos > CAP-1) pos = CAP-1;          // overflow clamp (never hit)
            unsigned rg  = (unsigned)__half_as_ushort(__float2half_rn(cr))
                         | ((unsigned)__half_as_ushort(__float2half_rn(cg)) << 16);
            unsigned cbp = (unsigned)__half_as_ushort(__float2half_rn(cb));
            lrec[wid][pos][0] = make_float4(mx, my, A, Bc);
            lrec[wid][pos][1] = make_float4(Cc, al,
                                            __uint_as_float(rg),
                                            __uint_as_float(cbp));
        }
        cnt += (int)__popcll(m);
    }
    if (cnt > CAP) cnt = CAP;
    if (lane == 0) wn[wid] = (unsigned)cnt;
    __syncthreads();

    unsigned n0 = wn[0], n1 = wn[1], n2 = wn[2];
    int total = (int)(n0 + n1 + n2 + wn[3]);

    // ---- 3: composite from LDS (vote-free unrolled body, R6-verified)
    int ix = tid & (TILE-1);
    int iy = tid >> 4;
    float pxf = (float)(tilex*TILE + ix) + 0.5f;
    float pyf = (float)(tiley*TILE + iy) + 0.5f;

    float T = 1.0f, accr = 0.0f, accg = 0.0f, accb = 0.0f;

    #pragma unroll 1
    for (int jb = 0; jb < total; jb += 32) {
        if (!__any(T > T_EPS)) break;              // wave-uniform, per-32 only
        int je = jb + 32 < total ? jb + 32 : total;
        #pragma unroll 4
        for (int j = jb; j < je; ++j) {
            // locate (wave list, offset) for ordered entry j (R2-verified)
            int w_ = 0; unsigned off = (unsigned)j;
            if (off >= n0) { off -= n0; w_ = 1;
              if (off >= n1) { off -= n1; w_ = 2;
                if (off >= n2) { off -= n2; w_ = 3; } } }
            float4 r0 = lrec[w_][off][0];   // mx, my, A, B   (broadcast)
            float4 r1 = lrec[w_][off][1];   // C, alpha, rg(f16x2), cb(f16)
            float dx = pxf - r0.x;
            float dy = pyf - r0.y;
            float p  = -0.5f*(r0.z*dx*dx + r1.x*dy*dy) - r0.w*dx*dy;
            if (p > P_CUT) {
                float a = fminf(r1.y * __expf(p), 0.999f);
                float wgt = a * T;
                unsigned rg = __float_as_uint(r1.z);
                accr += wgt * __half2float(__ushort_as_half((unsigned short)(rg & 0xffff)));
                accg += wgt * __half2float(__ushort_as_half((unsigned short)(rg >> 16)));
                accb += wgt * __half2float(__ushort_as_half((unsigned short)__float_as_uint(r1.w)));
                T *= (1.0f - a);
            }
        }
    }

    int X = tilex*TILE + ix;
    int Y = tiley*TILE + iy;
    partial[(size_t)seg*(IMG_W*IMG_H) + (size_t)Y*IMG_W + X] =
        make_float4(accr, accg, accb, T);
}

// ---------------------------------------------------------------------------
// Kernel 2: combine the 8 depth-ordered slices front-to-back, + background,
// clamp, store. UNCHANGED (verified R3/R6).
// ---------------------------------------------------------------------------
__global__ __launch_bounds__(256)
void combine(const float4* __restrict__ partial,
             const float*  __restrict__ background,
             float*        __restrict__ out)
{
    int p = blockIdx.x * 256 + threadIdx.x;     // pixel 0..65535

    float accr = 0.0f, accg = 0.0f, accb = 0.0f, T = 1.0f;
    #pragma unroll
    for (int s = 0; s < SEGS; ++s) {
        float4 q = partial[(size_t)s*(IMG_W*IMG_H) + p];
        accr += T * q.x;
        accg += T * q.y;
        accb += T * q.z;
        T    *= q.w;
    }
    float r = fminf(fmaxf(accr + T*background[0], 0.0f), 1.0f);
    float g = fminf(fmaxf(accg + T*background[1], 0.0f), 1.0f);
    float b = fminf(fmaxf(accb + T*background[2], 0.0f), 1.0f);

    size_t oi = (size_t)p*3;
    out[oi+0] = r;
    out[oi+1] = g;
    out[oi+2] = b;
}

// ---------------------------------------------------------------------------
extern "C" void kernel_launch(void* const* d_in, const int* in_sizes, int n_in,
                              void* d_out, int out_size, void* d_ws, size_t ws_size,
                              hipStream_t stream)
{
    const float* ctrl       = (const float*)d_in[0];  // (256,10,2)
    const float* features   = (const float*)d_in[1];  // (256,3)
    const float* cholesky   = (const float*)d_in[2];  // (256,3)
    const float* opacity    = (const float*)d_in[3];  // (256,1)
    const float* depth      = (const float*)d_in[4];  // (256,1)
    const float* background = (const float*)d_in[5];  // (3,)
    float* out = (float*)d_out;                       // (256,256,3)

    // workspace layout (16B-aligned); recs/bbox eliminated (prep fused)
    char* w = (char*)d_ws;
    float4* partial = (float4*)(w);                   // 8 MiB

    render_fused<<<NTILES*SEGS, 256, 0, stream>>>(ctrl, features, cholesky,
                                                  opacity, depth, partial);
    combine<<<(IMG_W*IMG_H)/256, 256, 0, stream>>>(partial, background, out);
}

// Round 8
// 86.532 us; speedup vs baseline: 1.3283x; 1.3283x over previous
//
#include <hip/hip_runtime.h>
#include <hip/hip_fp16.h>
#include <math.h>

// Problem constants (match reference)
#define NCURVES   256
#define GPER      64               // NUM_BEZIERS * NUM_SAMPLES = 2*32
#define NUM_G     (NCURVES*GPER)   // 16384
#define IMG_W     256
#define IMG_H     256
#define TILE      8                // 8x8 tile = one wave's 64 pixels
#define TILES_X   (IMG_W/TILE)     // 32
#define TILES_Y   (IMG_H/TILE)     // 32
#define NTILES    (TILES_X*TILES_Y) // 1024
#define REC_F     8                // floats per record (32 B: 2 float4)

#define A_MIN     3.0e-6f          // alpha cutoff for tile bbox
#define P_CUT     (-12.6f)         // per-pixel power cutoff (consistent with A_MIN)
#define T_EPS     1.0e-5f          // transmittance early-out (residual <= 1e-5)

#define DW        8                // depth-slice waves per block
#define GSL       (NUM_G/DW)       // 2048 sorted gaussians per wave slice

// ---------------------------------------------------------------------------
// Kernel 1 (prep): verified math (R3/R6), bbox at TILE=8 granularity
// (fields <= 31, fit u8 packing). 256 blocks x 64 threads.
// record: {mx,my,A,B},{C,alpha,rg(f16x2),cb(f16)}.
// ---------------------------------------------------------------------------
__global__ __launch_bounds__(GPER)
void prep(const float* __restrict__ ctrl,        // [256][10][2]
          const float* __restrict__ features,    // [256][3]
          const float* __restrict__ cholesky,    // [256][3]
          const float* __restrict__ opacity,     // [256]
          const float* __restrict__ depth,       // [256]
          float*       __restrict__ recs,        // [NUM_G][8]
          unsigned*    __restrict__ bbox)        // [NUM_G]
{
    int c   = blockIdx.x;
    int tid = threadIdx.x;          // 0..63 (exactly one wave)

    // ---- stable rank (matches stable argsort over 64x-repeated depths)
    float dc = depth[c];
    int r = 0;
    #pragma unroll
    for (int jj = 0; jj < 4; ++jj) {
        int j = tid + jj*64;
        float dj = depth[j];
        r += (dj < dc) || (dj == dc && j < c);
    }
    #pragma unroll
    for (int off = 32; off > 0; off >>= 1) r += __shfl_down(r, off, 64);
    r = __shfl(r, 0, 64);

    // ---- per-curve params
    float c0 = cholesky[3*c+0] + 0.5f;
    float c1 = cholesky[3*c+1];
    float c2 = cholesky[3*c+2] + 0.5f;
    float s00 = c0*c0;
    float s01 = c0*c1;
    float s11 = c1*c1 + c2*c2;
    float inv = 1.0f / (s00*s11 - s01*s01);
    float A  =  s11*inv;
    float Bc = -s01*inv;
    float Cc =  s00*inv;

    float cr = 1.0f/(1.0f + __expf(-features[3*c+0]));
    float cg = 1.0f/(1.0f + __expf(-features[3*c+1]));
    float cb = 1.0f/(1.0f + __expf(-features[3*c+2]));
    float al = 1.0f/(1.0f + __expf(-opacity[c]));

    float cut = fmaxf(2.0f*(__logf(al) - __logf(A_MIN)), 0.0f);
    float rx = sqrtf(cut * s00);
    float ry = sqrtf(cut * s11);

    // ---- bezier sample -> mean
    int k = tid >> 5;               // bezier segment 0/1
    int s = tid & 31;               // sample 0..31
    float t = 0.007f + (float)s * (0.986f/31.0f);
    float u = 1.0f - t;
    float t2=t*t, t3=t2*t, t4=t3*t, t5=t4*t;
    float u2=u*u, u3=u2*u, u4=u3*u, u5=u4*u;
    float w[6] = { u5, 5.0f*t*u4, 10.0f*t2*u3, 10.0f*t3*u2, 5.0f*t4*u, t5 };

    const float* cp = ctrl + c*20;
    float px = 0.0f, py = 0.0f;
    #pragma unroll
    for (int j = 0; j < 6; ++j) {
        int idx = (k*5 + j) % 10;   // seg0: 0..5 ; seg1: 5,6,7,8,9,0
        px += w[j]*cp[2*idx+0];
        py += w[j]*cp[2*idx+1];
    }
    float mx = (tanhf(px)*0.5f + 0.5f) * (float)IMG_W;
    float my = (tanhf(py)*0.5f + 0.5f) * (float)IMG_H;

    int gi = r*GPER + tid;          // depth-sorted gaussian index (stable ties)

    unsigned rg  = (unsigned)__half_as_ushort(__float2half_rn(cr))
                 | ((unsigned)__half_as_ushort(__float2half_rn(cg)) << 16);
    unsigned cbp = (unsigned)__half_as_ushort(__float2half_rn(cb));

    float4* o4 = (float4*)(recs + (size_t)gi*REC_F);
    o4[0] = make_float4(mx, my, A, Bc);
    o4[1] = make_float4(Cc, al, __uint_as_float(rg), __uint_as_float(cbp));

    int tx0 = min(max((int)floorf((mx - rx) * (1.0f/TILE)), 0), TILES_X-1);
    int tx1 = min(max((int)floorf((mx + rx) * (1.0f/TILE)), 0), TILES_X-1);
    int ty0 = min(max((int)floorf((my - ry) * (1.0f/TILE)), 0), TILES_Y-1);
    int ty1 = min(max((int)floorf((my + ry) * (1.0f/TILE)), 0), TILES_Y-1);
    bbox[gi] = (unsigned)tx0 | ((unsigned)ty0<<8) | ((unsigned)tx1<<16) | ((unsigned)ty1<<24);
}

// ---------------------------------------------------------------------------
// Kernel 2 (render_tile8): 1024 blocks (one per 8x8 tile) x 512 threads
// (8 waves = 8 depth-slices). Replaces render + combine + partial buffer.
//
// Wave w (wave-private, no barriers until the end):
//   - scans sorted-gi slice [w*2048,(w+1)*2048): 32 bbox tests/lane with
//     batched loads, ballot-compacting hits into its own LDS list
//     (capacity = full slice -> overflow impossible);
//   - composites its ordered list for the tile's 64 pixels (1 px/lane)
//     straight from L2 (records wave-broadcast; 8 waves/SIMD TLP hides the
//     chain -- R3's lesson), vote-free unrolled body, early-out checked only
//     every 32 iters (R5's per-iter-vote serialization lesson).
// Then: barrier; the 8 partials are combined in-LDS (memory REUSED from the
// dead hit lists via union -> LDS stays 32.8 KB -> 4 blocks/CU -> 8
// waves/SIMD, all 1024 blocks resident in one scheduling round).
// Hot tile: ~500 hits / 8 waves = ~63 iters/wave (~4k cyc) vs R2's 54k
// one-CU serialization. No partial buffer, no combine kernel, no fences.
// ---------------------------------------------------------------------------
__global__ __launch_bounds__(512)
void render_tile8(const float*    __restrict__ recs,
                  const unsigned* __restrict__ bbox,
                  const float*    __restrict__ background,
                  float*          __restrict__ out)
{
    __shared__ union {
        unsigned short lst[DW][GSL];    // 32 KB during scan+composite
        float4         pc[DW][64];      //  8 KB after reuse barrier
    } sh;

    int tid   = threadIdx.x;
    int lane  = tid & 63;
    int w     = tid >> 6;               // depth slice 0..7
    int tile  = blockIdx.x;             // 0..1023
    int tilex = tile & (TILES_X-1);
    int tiley = tile >> 5;
    unsigned long long lmask = (1ull << lane) - 1ull;

    int gb = w * GSL;                   // this wave's sorted-gi base

    // ---- scan: 32 bbox tests per lane, 4 batches of 8 prefetched loads
    int cnt = 0;
    #pragma unroll 1
    for (int b = 0; b < 4; ++b) {
        unsigned bb[8];
        #pragma unroll
        for (int u = 0; u < 8; ++u)
            bb[u] = bbox[gb + (b*8 + u)*64 + lane];
        #pragma unroll
        for (int u = 0; u < 8; ++u) {
            unsigned v = bb[u];
            bool pred = (tilex >= (int)( v        & 0xff)) &
                        (tilex <= (int)((v >> 16) & 0xff)) &
                        (tiley >= (int)((v >>  8) & 0xff)) &
                        (tiley <= (int)((v >> 24) & 0xff));
            unsigned long long m = __ballot(pred ? 1 : 0);
            if (pred)
                sh.lst[w][cnt + (int)__popcll(m & lmask)] =
                    (unsigned short)((b*8 + u)*64 + lane);
            cnt += (int)__popcll(m);
        }
    }

    // ---- composite this wave's ordered slice for its 64 pixels
    float pxf = (float)(tilex*TILE + (lane & 7)) + 0.5f;
    float pyf = (float)(tiley*TILE + (lane >> 3)) + 0.5f;

    float T = 1.0f, accr = 0.0f, accg = 0.0f, accb = 0.0f;

    #pragma unroll 1
    for (int jb = 0; jb < cnt; jb += 32) {
        if (!__any(T > T_EPS)) break;          // wave-uniform, per-32 only
        int je = jb + 32 < cnt ? jb + 32 : cnt;
        #pragma unroll 4
        for (int j = jb; j < je; ++j) {
            int g = gb + (int)sh.lst[w][j];                 // LDS broadcast
            const float4* rp = (const float4*)(recs + (size_t)g*REC_F);
            float4 r0 = rp[0];          // mx, my, A, B   (wave-broadcast, L2)
            float4 r1 = rp[1];          // C, alpha, rg(f16x2), cb(f16)
            float dx = pxf - r0.x;
            float dy = pyf - r0.y;
            float p  = -0.5f*(r0.z*dx*dx + r1.x*dy*dy) - r0.w*dx*dy;
            if (p > P_CUT) {
                float a = fminf(r1.y * __expf(p), 0.999f);
                float wgt = a * T;
                unsigned rg = __float_as_uint(r1.z);
                accr += wgt * __half2float(__ushort_as_half((unsigned short)(rg & 0xffff)));
                accg += wgt * __half2float(__ushort_as_half((unsigned short)(rg >> 16)));
                accb += wgt * __half2float(__ushort_as_half((unsigned short)__float_as_uint(r1.w)));
                T *= (1.0f - a);
            }
        }
    }

    __syncthreads();                    // all waves done READING lst
    sh.pc[w][lane] = make_float4(accr, accg, accb, T);
    __syncthreads();                    // pc visible

    // ---- wave 0: fold 8 depth-ordered partials, + background, store
    if (w == 0) {
        float4 a = sh.pc[0][lane];
        float r = a.x, g = a.y, b = a.z, Tt = a.w;
        #pragma unroll
        for (int s = 1; s < DW; ++s) {
            float4 q = sh.pc[s][lane];
            r  += Tt * q.x;
            g  += Tt * q.y;
            b  += Tt * q.z;
            Tt *= q.w;
        }
        r = fminf(fmaxf(r + Tt*background[0], 0.0f), 1.0f);
        g = fminf(fmaxf(g + Tt*background[1], 0.0f), 1.0f);
        b = fminf(fmaxf(b + Tt*background[2], 0.0f), 1.0f);

        int X = tilex*TILE + (lane & 7);
        int Y = tiley*TILE + (lane >> 3);
        size_t oi = ((size_t)Y*IMG_W + X)*3;
        out[oi+0] = r;
        out[oi+1] = g;
        out[oi+2] = b;
    }
}

// ---------------------------------------------------------------------------
extern "C" void kernel_launch(void* const* d_in, const int* in_sizes, int n_in,
                              void* d_out, int out_size, void* d_ws, size_t ws_size,
                              hipStream_t stream)
{
    const float* ctrl       = (const float*)d_in[0];  // (256,10,2)
    const float* features   = (const float*)d_in[1];  // (256,3)
    const float* cholesky   = (const float*)d_in[2];  // (256,3)
    const float* opacity    = (const float*)d_in[3];  // (256,1)
    const float* depth      = (const float*)d_in[4];  // (256,1)
    const float* background = (const float*)d_in[5];  // (3,)
    float* out = (float*)d_out;                       // (256,256,3)

    // workspace layout (16B-aligned); no partial buffer, no combine kernel
    char* w = (char*)d_ws;
    float*    recs  = (float*)   (w);                 // 524288 B
    unsigned* bboxp = (unsigned*)(w + 524288);        //  65536 B

    prep<<<NCURVES, GPER, 0, stream>>>(ctrl, features, cholesky, opacity, depth,
                                       recs, bboxp);
    render_tile8<<<NTILES, 512, 0, stream>>>(recs, bboxp, background, out);
}

// Round 9
// 82.663 us; speedup vs baseline: 1.3905x; 1.0468x over previous
//
#include <hip/hip_runtime.h>
#include <hip/hip_fp16.h>
#include <math.h>

// Problem constants (match reference)
#define NCURVES   256
#define GPER      64               // NUM_BEZIERS * NUM_SAMPLES = 2*32
#define NUM_G     (NCURVES*GPER)   // 16384
#define IMG_W     256
#define IMG_H     256
#define TILE      16
#define TILES_X   (IMG_W/TILE)     // 16
#define TILES_Y   (IMG_H/TILE)     // 16
#define NTILES    (TILES_X*TILES_Y) // 256
#define REC_F     8                // floats per gaussian record (32 B: 2 float4)

#define A_MIN     3.0e-6f          // alpha cutoff for tile bbox
#define P_CUT     (-12.6f)         // per-pixel power cutoff (consistent with A_MIN)
#define T_EPS     1.0e-5f          // transmittance early-out (residual <= 1e-5)

#define SEGS      8                // depth slices (by gi range) -> cross-CU split
#define GSEG      (NUM_G/SEGS)     // 2048 gaussians per slice
#define GWAVE     (GSEG/4)         // 512 per scan wave (4 waves/block)
#define STAGE     512              // staged records per chunk (16 KB LDS)

// ---------------------------------------------------------------------------
// SESSION-FINAL configuration (= round-6 kernel, best measured: 83.1 us).
// Eight rounds established: our kernels total ~12 us inside an ~83 us
// iteration whose floor is (a) the harness's 256 MiB workspace poison fill
// (39.6 us at 85% of HBM peak -- at the memory roofline, uncontrollable) and
// (b) ~40 us of per-iteration reset/replay overhead insensitive to our
// dispatch count and kernel time (R8: fewer dispatches + less kernel time
// did NOT reduce dur_us). Structure below: balanced cross-CU depth split
// (tile x gi-eighth), LDS-staged vote-free composite, associative combine.
// ---------------------------------------------------------------------------

// ---------------------------------------------------------------------------
// Kernel 1 (prep): 256 blocks x 64 threads. Stable depth rank via wave
// reduction; conic/color/alpha; bezier mean; writes packed 32B record +
// tile bbox at sorted index gi = rank*64 + tid.
// record: {mx,my,A,B},{C,alpha,rg(f16x2),cb(f16)}.
// ---------------------------------------------------------------------------
__global__ __launch_bounds__(GPER)
void prep(const float* __restrict__ ctrl,        // [256][10][2]
          const float* __restrict__ features,    // [256][3]
          const float* __restrict__ cholesky,    // [256][3]
          const float* __restrict__ opacity,     // [256]
          const float* __restrict__ depth,       // [256]
          float*       __restrict__ recs,        // [NUM_G][8]
          unsigned*    __restrict__ bbox)        // [NUM_G]
{
    int c   = blockIdx.x;
    int tid = threadIdx.x;          // 0..63 (exactly one wave)

    // ---- stable rank (matches stable argsort over 64x-repeated depths)
    float dc = depth[c];
    int r = 0;
    #pragma unroll
    for (int jj = 0; jj < 4; ++jj) {
        int j = tid + jj*64;
        float dj = depth[j];
        r += (dj < dc) || (dj == dc && j < c);
    }
    #pragma unroll
    for (int off = 32; off > 0; off >>= 1) r += __shfl_down(r, off, 64);
    r = __shfl(r, 0, 64);

    // ---- per-curve params
    float c0 = cholesky[3*c+0] + 0.5f;
    float c1 = cholesky[3*c+1];
    float c2 = cholesky[3*c+2] + 0.5f;
    float s00 = c0*c0;
    float s01 = c0*c1;
    float s11 = c1*c1 + c2*c2;
    float inv = 1.0f / (s00*s11 - s01*s01);
    float A  =  s11*inv;
    float Bc = -s01*inv;
    float Cc =  s00*inv;

    float cr = 1.0f/(1.0f + __expf(-features[3*c+0]));
    float cg = 1.0f/(1.0f + __expf(-features[3*c+1]));
    float cb = 1.0f/(1.0f + __expf(-features[3*c+2]));
    float al = 1.0f/(1.0f + __expf(-opacity[c]));

    float cut = fmaxf(2.0f*(__logf(al) - __logf(A_MIN)), 0.0f);
    float rx = sqrtf(cut * s00);
    float ry = sqrtf(cut * s11);

    // ---- bezier sample -> mean
    int k = tid >> 5;               // bezier segment 0/1
    int s = tid & 31;               // sample 0..31
    float t = 0.007f + (float)s * (0.986f/31.0f);
    float u = 1.0f - t;
    float t2=t*t, t3=t2*t, t4=t3*t, t5=t4*t;
    float u2=u*u, u3=u2*u, u4=u3*u, u5=u4*u;
    float w[6] = { u5, 5.0f*t*u4, 10.0f*t2*u3, 10.0f*t3*u2, 5.0f*t4*u, t5 };

    const float* cp = ctrl + c*20;
    float px = 0.0f, py = 0.0f;
    #pragma unroll
    for (int j = 0; j < 6; ++j) {
        int idx = (k*5 + j) % 10;   // seg0: 0..5 ; seg1: 5,6,7,8,9,0
        px += w[j]*cp[2*idx+0];
        py += w[j]*cp[2*idx+1];
    }
    float mx = (tanhf(px)*0.5f + 0.5f) * (float)IMG_W;
    float my = (tanhf(py)*0.5f + 0.5f) * (float)IMG_H;

    int gi = r*GPER + tid;          // depth-sorted gaussian index (stable ties)

    unsigned rg  = (unsigned)__half_as_ushort(__float2half_rn(cr))
                 | ((unsigned)__half_as_ushort(__float2half_rn(cg)) << 16);
    unsigned cbp = (unsigned)__half_as_ushort(__float2half_rn(cb));

    float4* o4 = (float4*)(recs + (size_t)gi*REC_F);
    o4[0] = make_float4(mx, my, A, Bc);
    o4[1] = make_float4(Cc, al, __uint_as_float(rg), __uint_as_float(cbp));

    int tx0 = min(max((int)floorf((mx - rx) * (1.0f/TILE)), 0), TILES_X-1);
    int tx1 = min(max((int)floorf((mx + rx) * (1.0f/TILE)), 0), TILES_X-1);
    int ty0 = min(max((int)floorf((my - ry) * (1.0f/TILE)), 0), TILES_Y-1);
    int ty1 = min(max((int)floorf((my + ry) * (1.0f/TILE)), 0), TILES_Y-1);
    bbox[gi] = (unsigned)tx0 | ((unsigned)ty0<<8) | ((unsigned)tx1<<16) | ((unsigned)ty1<<24);
}

// ---------------------------------------------------------------------------
// Kernel 2 (render8): grid = (tile, gi-eighth) = 2048 blocks x 256 threads.
// Balanced cross-CU depth split; two-pass ballot scan into a flat ordered
// LDS list; cooperative LDS staging of compacted records (independent 32B
// loads, throughput-bound); vote-free unroll-4 composite with early-out
// checked only at 32-iteration boundaries (per-iter wave votes serialize
// the pipeline -- R5 lesson). LDS 20.3 KB -> 7 blocks/CU.
// ---------------------------------------------------------------------------
__global__ __launch_bounds__(256)
void render8(const float*    __restrict__ recs,
             const unsigned* __restrict__ bbox,
             float4*         __restrict__ partial)   // [SEGS][IMG_H*IMG_W]
{
    __shared__ unsigned short flat[GSEG];   // 4 KB: ordered hit list (gi-local)
    __shared__ float4         sd[STAGE][2]; // 16 KB: staged records
    __shared__ unsigned       wn[4];

    int tid   = threadIdx.x;
    int seg   = blockIdx.x & (SEGS-1);
    int tile  = blockIdx.x >> 3;            // 0..255
    int tilex = tile & (TILES_X-1);
    int tiley = tile >> 4;

    int lane = tid & 63;
    int wid  = tid >> 6;                    // 0..3
    unsigned long long lmask = (1ull << lane) - 1ull;

    int sbase = seg * GSEG;
    int gwave = wid * GWAVE;                // local base of this wave's subrange

    // ---- Phase 1a: predicate + count
    bool pr[8];
    int cnt = 0;
    {
        unsigned bb[8];
        #pragma unroll
        for (int u = 0; u < 8; ++u)
            bb[u] = bbox[sbase + gwave + u*64 + lane];
        #pragma unroll
        for (int u = 0; u < 8; ++u) {
            unsigned b = bb[u];
            pr[u] = (tilex >= (int)( b        & 0xff)) &
                    (tilex <= (int)((b >> 16) & 0xff)) &
                    (tiley >= (int)((b >>  8) & 0xff)) &
                    (tiley <= (int)((b >> 24) & 0xff));
            cnt += (int)__popcll(__ballot(pr[u] ? 1 : 0));
        }
    }
    if (lane == 0) wn[wid] = (unsigned)cnt;
    __syncthreads();

    unsigned p1 = wn[0], p2 = p1 + wn[1], p3 = p2 + wn[2];
    int total = (int)(p3 + wn[3]);

    // ---- Phase 1b: compact into flat ordered list
    if (total) {
        unsigned base = (wid == 0) ? 0u : (wid == 1) ? p1 : (wid == 2) ? p2 : p3;
        int off = 0;
        #pragma unroll
        for (int u = 0; u < 8; ++u) {
            unsigned long long m = __ballot(pr[u] ? 1 : 0);
            if (pr[u])
                flat[base + off + (int)__popcll(m & lmask)] =
                    (unsigned short)(gwave + u*64 + lane);
            off += (int)__popcll(m);
        }
    }
    __syncthreads();

    // ---- Phase 2: LDS-staged composite
    int ix = tid & (TILE-1);
    int iy = tid >> 4;
    float pxf = (float)(tilex*TILE + ix) + 0.5f;
    float pyf = (float)(tiley*TILE + iy) + 0.5f;

    float T = 1.0f, accr = 0.0f, accg = 0.0f, accb = 0.0f;

    #pragma unroll 1
    for (int base = 0; base < total; base += STAGE) {
        // block-wide early-out doubles as the pre-stage barrier
        int nalive = __syncthreads_count(T > T_EPS);
        if (nalive == 0) break;                     // uniform

        int nstage = total - base;
        if (nstage > STAGE) nstage = STAGE;

        // stage: independent scattered 32B loads, throughput-bound
        for (int e = tid; e < nstage; e += 256) {
            int g = sbase + (int)flat[base + e];
            const float4* rp = (const float4*)(recs + (size_t)g*REC_F);
            sd[e][0] = rp[0];
            sd[e][1] = rp[1];
        }
        __syncthreads();                            // sd[] visible

        // composite from LDS; early-out only at 32-iter boundaries so the
        // unrolled body stays vote-free and pipelineable
        #pragma unroll 1
        for (int jb = 0; jb < nstage; jb += 32) {
            if (!__any(T > T_EPS)) break;           // wave-uniform
            int je = jb + 32 < nstage ? jb + 32 : nstage;
            #pragma unroll 4
            for (int j = jb; j < je; ++j) {
                float4 r0 = sd[j][0];       // mx, my, A, B   (broadcast)
                float4 r1 = sd[j][1];       // C, alpha, rg(f16x2), cb(f16)
                float dx = pxf - r0.x;
                float dy = pyf - r0.y;
                float p  = -0.5f*(r0.z*dx*dx + r1.x*dy*dy) - r0.w*dx*dy;
                if (p > P_CUT) {
                    float a = fminf(r1.y * __expf(p), 0.999f);
                    float wgt = a * T;
                    unsigned rg = __float_as_uint(r1.z);
                    accr += wgt * __half2float(__ushort_as_half((unsigned short)(rg & 0xffff)));
                    accg += wgt * __half2float(__ushort_as_half((unsigned short)(rg >> 16)));
                    accb += wgt * __half2float(__ushort_as_half((unsigned short)__float_as_uint(r1.w)));
                    T *= (1.0f - a);
                }
            }
        }
        __syncthreads();                            // protect sd[] reuse
    }

    int X = tilex*TILE + ix;
    int Y = tiley*TILE + iy;
    partial[(size_t)seg*(IMG_W*IMG_H) + (size_t)Y*IMG_W + X] =
        make_float4(accr, accg, accb, T);
}

// ---------------------------------------------------------------------------
// Kernel 3: combine the 8 depth-ordered slices front-to-back, + background,
// clamp, store. Slice boundaries at fixed gi are depth-contiguous -> the
// associative combine is exact.
// ---------------------------------------------------------------------------
__global__ __launch_bounds__(256)
void combine(const float4* __restrict__ partial,
             const float*  __restrict__ background,
             float*        __restrict__ out)
{
    int p = blockIdx.x * 256 + threadIdx.x;     // pixel 0..65535

    float accr = 0.0f, accg = 0.0f, accb = 0.0f, T = 1.0f;
    #pragma unroll
    for (int s = 0; s < SEGS; ++s) {
        float4 q = partial[(size_t)s*(IMG_W*IMG_H) + p];
        accr += T * q.x;
        accg += T * q.y;
        accb += T * q.z;
        T    *= q.w;
    }
    float r = fminf(fmaxf(accr + T*background[0], 0.0f), 1.0f);
    float g = fminf(fmaxf(accg + T*background[1], 0.0f), 1.0f);
    float b = fminf(fmaxf(accb + T*background[2], 0.0f), 1.0f);

    size_t oi = (size_t)p*3;
    out[oi+0] = r;
    out[oi+1] = g;
    out[oi+2] = b;
}

// ---------------------------------------------------------------------------
extern "C" void kernel_launch(void* const* d_in, const int* in_sizes, int n_in,
                              void* d_out, int out_size, void* d_ws, size_t ws_size,
                              hipStream_t stream)
{
    const float* ctrl       = (const float*)d_in[0];  // (256,10,2)
    const float* features   = (const float*)d_in[1];  // (256,3)
    const float* cholesky   = (const float*)d_in[2];  // (256,3)
    const float* opacity    = (const float*)d_in[3];  // (256,1)
    const float* depth      = (const float*)d_in[4];  // (256,1)
    const float* background = (const float*)d_in[5];  // (3,)
    float* out = (float*)d_out;                       // (256,256,3)

    // workspace layout (16B-aligned)
    char* w = (char*)d_ws;
    float*    recs    = (float*)   (w);                    // 524288 B
    unsigned* bboxp   = (unsigned*)(w + 524288);           //  65536 B
    float4*   partial = (float4*)  (w + 524288 + 65536);   // 8 MiB

    prep<<<NCURVES, GPER, 0, stream>>>(ctrl, features, cholesky, opacity, depth,
                                       recs, bboxp);
    render8<<<NTILES*SEGS, 256, 0, stream>>>(recs, bboxp, partial);
    combine<<<(IMG_W*IMG_H)/256, 256, 0, stream>>>(partial, background, out);
}